// Round 1
// 128.854 us; speedup vs baseline: 1.0325x; 1.0325x over previous
//
#include <hip/hip_runtime.h>

// ImplicitFunction MLP via fp16 MFMA (v_mfma_f32_32x32x16_f16), round 5.
// Round-5 changes (occupancy attack):
//  - Direct accumulation into acc[][] (removed a00..a11 temp copy-in/copy-out,
//    which doubled the AGPR footprint: ~84 arch + ~128 acc > 170 unified regs
//    -> only 2 waves/SIMD resident = the measured 25% occupancy).
//  - 512-thread blocks + __launch_bounds__(512,4): caps unified regs at 128
//    (4 waves/SIMD = 16 waves/CU) while the 52KB LDS image is shared by 8
//    waves (2 blocks/CU = 104KB <= 160KB, LDS no longer the binding limit).
//
// Carried from round 4:
//  - K-permuted weights: next layer's A-fragment k-axis permuted so each
//    lane's B-frag for K-step s is its own two local C-output quads:
//      feat(s,h,j) = 16s + 8*(j>>2) + 4h + (j&3)   (bijection over 0..63)
//    -> zero cross-lane exchange between layers.
//  - Bias in MFMA C-operand (pre-arranged C-layout in LDS, broadcast reads).
//  - lrelu in packed fp16 (v_pk_mul_f16 + v_pk_max_f16) after cvt_pkrtz.
//  - Activations carried scaled by 1/64 (lrelu is positively homogeneous).
//  - 64 points/wave (2 N-tiles) sharing W-frags and bias C-regs.
//
// Layouts (gfx950, 32x32x16):
//   A/B frag: lane (i=lane&31, h=lane>>5) holds k = 8h+j, j=0..7
//   C/D:      col n = lane&31, row m = (r&3) + 8*(r>>2) + 4h, r=0..15

typedef _Float16 half8 __attribute__((ext_vector_type(8)));
typedef _Float16 half2v __attribute__((ext_vector_type(2)));
typedef float floatx16 __attribute__((ext_vector_type(16)));

#define N_HID 6
// ws / LDS byte offsets (single contiguous image, staged wholesale)
#define OFF_A 0        // hidden W frags [l:6][t:2][s:4][lane:64][j:8] fp16 = 49152
#define OFF_B 49152    // layer0 A frags [t:2][lane:64][j:8] fp16          = 2048
#define OFF_C 51200    // bias/64 fp32, C-layout [l:7][h:2][t:2][r:16]     = 1792
#define OFF_D 52992    // wo*so*64 fp32, C-layout [h:2][t:2][r:16]         = 256
#define IMG_BYTES 53248
#define SETUP_TOTAL (24576 + 1024 + 448 + 64)

__global__ __launch_bounds__(256) void setup_weights(
    const float* __restrict__ w0, const float* __restrict__ s0, const float* __restrict__ b0,
    const float* __restrict__ wh, const float* __restrict__ sh, const float* __restrict__ bh,
    const float* __restrict__ wo, const float* __restrict__ so,
    unsigned char* __restrict__ ws)
{
    int i = blockIdx.x * 256 + threadIdx.x;
    if (i < 24576) {
        // hidden W frags with K-permutation baked in:
        // A[m][kslot(s,h,j)] = wh[l][feat][m] * sh[l][m], feat = 16s+8*(j>>2)+4h+(j&3)
        int j = i & 7, lane = (i >> 3) & 63, s = (i >> 9) & 3, t = (i >> 11) & 1, l = i >> 12;
        int m = 32 * t + (lane & 31);
        int h = lane >> 5;
        int feat = 16 * s + 8 * (j >> 2) + 4 * h + (j & 3);
        ((_Float16*)(ws + OFF_A))[i] = (_Float16)(wh[(l * 64 + feat) * 64 + m] * sh[l * 64 + m]);
    } else if (i < 24576 + 1024) {
        // layer-0 A frags (standard k order; B built from raw points)
        int i2 = i - 24576;
        int j = i2 & 7, lane = (i2 >> 3) & 63, t = i2 >> 9;
        int m = 32 * t + (lane & 31);
        int k = 8 * (lane >> 5) + j;
        float v = (k < 3) ? w0[k * 64 + m] * s0[m] * 0.015625f : 0.f;
        ((_Float16*)(ws + OFF_B))[i2] = (_Float16)v;
    } else if (i < 24576 + 1024 + 448) {
        // biases/64 in C layout
        int i2 = i - 24576 - 1024;
        int r = i2 & 15, t = (i2 >> 4) & 1, h = (i2 >> 5) & 1, l = i2 >> 6;
        int feat = 32 * t + (r & 3) + 8 * ((r >> 2) & 3) + 4 * h;
        float bv = (l == 0) ? b0[feat] : bh[(l - 1) * 64 + feat];
        ((float*)(ws + OFF_C))[i2] = bv * 0.015625f;
    } else if (i < SETUP_TOTAL) {
        // wo*so*64 in C layout
        int i2 = i - 24576 - 1024 - 448;
        int r = i2 & 15, t = (i2 >> 4) & 1, h = i2 >> 5;
        int feat = 32 * t + (r & 3) + 8 * ((r >> 2) & 3) + 4 * h;
        ((float*)(ws + OFF_D))[i2] = wo[feat] * so[0] * 64.f;
    }
}

union FragU { int i[4]; half8 v; };

static __device__ __forceinline__ int pkrtz(float a, float b) {
    auto hh = __builtin_amdgcn_cvt_pkrtz(a, b);  // v2f16, RTZ pack
    int r;
    __builtin_memcpy(&r, &hh, 4);
    return r;
}

// packed-fp16 leaky relu on a pair: max(u, 0.2*u) -> v_pk_mul_f16 + v_pk_max_f16
static __device__ __forceinline__ int lrelu2(int v) {
    half2v u;
    __builtin_memcpy(&u, &v, 4);
    half2v w = u * (_Float16)0.2f;
    half2v r = __builtin_elementwise_max(u, w);
    int o;
    __builtin_memcpy(&o, &r, 4);
    return o;
}

static __device__ __forceinline__ floatx16 mfma16(half8 a, half8 b, floatx16 c) {
    return __builtin_amdgcn_mfma_f32_32x32x16_f16(a, b, c, 0, 0, 0);
}

__global__ __launch_bounds__(512, 4) void mlp_mfma(
    const float* __restrict__ points,
    const unsigned char* __restrict__ ws,
    const float* __restrict__ bo,
    float* __restrict__ out, int n)
{
    __shared__ __align__(16) unsigned char lds[IMG_BYTES];

    // stage full weight image to LDS (53248 B = 3328 * 16; 512 threads)
    {
        const uint4* src = (const uint4*)ws;
        uint4* dst = (uint4*)lds;
#pragma unroll
        for (int i = 0; i < 6; ++i) {
            int idx = threadIdx.x + 512 * i;
            dst[idx] = src[idx];
        }
        if (threadIdx.x < 256) {
            int idx = 3072 + threadIdx.x;
            dst[idx] = src[idx];
        }
    }
    __syncthreads();

    const int lane = threadIdx.x & 63;
    const int wv = threadIdx.x >> 6;   // 0..7 (8 waves/block)
    const int p = lane & 31;
    const int h = lane >> 5;
    const int base = (blockIdx.x * 8 + wv) * 64;
    const int pt0 = base + p, pt1 = base + 32 + p;
    const int pl0 = min(pt0, n - 1), pl1 = min(pt1, n - 1);

    const half8* Wf = (const half8*)(lds + OFF_A);          // [l][t][s][lane]
    const half8* A0 = (const half8*)(lds + OFF_B);          // [t][lane]
    const floatx16* biasC = (const floatx16*)(lds + OFF_C); // [(l*2+h)*2+t]
    const floatx16* woC = (const floatx16*)(lds + OFF_D);   // [h*2+t]

    floatx16 acc[2][2];   // [ntile][mtile]
    int fr[2][16];        // packed activations, index 8t + rp

    // ---- layer 0 ----
    {
        FragU bu0, bu1;
        bu0.i[0] = bu0.i[1] = bu0.i[2] = bu0.i[3] = 0;
        bu1 = bu0;
        if (h == 0) {
            bu0.v[0] = (_Float16)points[3 * pl0 + 0];
            bu0.v[1] = (_Float16)points[3 * pl0 + 1];
            bu0.v[2] = (_Float16)points[3 * pl0 + 2];
            bu1.v[0] = (_Float16)points[3 * pl1 + 0];
            bu1.v[1] = (_Float16)points[3 * pl1 + 1];
            bu1.v[2] = (_Float16)points[3 * pl1 + 2];
        }
        floatx16 c0 = biasC[h * 2 + 0];   // l = 0
        floatx16 c1 = biasC[h * 2 + 1];
        half8 a0 = A0[lane], a1 = A0[64 + lane];
        acc[0][0] = mfma16(a0, bu0.v, c0);
        acc[0][1] = mfma16(a1, bu0.v, c1);
        acc[1][0] = mfma16(a0, bu1.v, c0);
        acc[1][1] = mfma16(a1, bu1.v, c1);
    }

    // pack + lrelu -> fr (also the next layer's B-frags, exchange-free)
    auto packfr = [&]() {
#pragma unroll
        for (int nt = 0; nt < 2; ++nt)
#pragma unroll
            for (int t = 0; t < 2; ++t)
#pragma unroll
                for (int rp = 0; rp < 8; ++rp) {
                    int v = pkrtz(acc[nt][t][2 * rp], acc[nt][t][2 * rp + 1]);
                    fr[nt][8 * t + 2 * (rp >> 1) + (rp & 1)] = lrelu2(v);
                }
    };
    packfr();

    // ---- 6 hidden layers (accumulate directly into acc[][], no temp copies) ----
    for (int l = 0; l < N_HID; ++l) {
        floatx16 c0 = biasC[((l + 1) * 2 + h) * 2 + 0];
        floatx16 c1 = biasC[((l + 1) * 2 + h) * 2 + 1];
        const half8* wl = Wf + l * 512 + lane;  // + t*256 + s*64
        acc[0][0] = c0; acc[0][1] = c1; acc[1][0] = c0; acc[1][1] = c1;
#pragma unroll
        for (int s = 0; s < 4; ++s) {
            half8 wt0 = wl[s * 64];
            half8 wt1 = wl[256 + s * 64];
            FragU f0, f1;
#pragma unroll
            for (int c = 0; c < 4; ++c) { f0.i[c] = fr[0][4 * s + c]; f1.i[c] = fr[1][4 * s + c]; }
            acc[0][0] = mfma16(wt0, f0.v, acc[0][0]);
            acc[0][1] = mfma16(wt1, f0.v, acc[0][1]);
            acc[1][0] = mfma16(wt0, f1.v, acc[1][0]);
            acc[1][1] = mfma16(wt1, f1.v, acc[1][1]);
        }
        if (l < N_HID - 1) packfr();
    }

    // ---- output layer: fp32 lrelu + dot with wo (C-layout), cross-half reduce ----
    {
        floatx16 wo0 = woC[h * 2 + 0];
        floatx16 wo1 = woC[h * 2 + 1];
        float part0 = 0.f, part1 = 0.f;
#pragma unroll
        for (int r = 0; r < 16; ++r) {
            float u;
            u = acc[0][0][r]; part0 = fmaf(fmaxf(u, 0.2f * u), wo0[r], part0);
            u = acc[0][1][r]; part0 = fmaf(fmaxf(u, 0.2f * u), wo1[r], part0);
            u = acc[1][0][r]; part1 = fmaf(fmaxf(u, 0.2f * u), wo0[r], part1);
            u = acc[1][1][r]; part1 = fmaf(fmaxf(u, 0.2f * u), wo1[r], part1);
        }
        part0 += __shfl_xor(part0, 32);
        part1 += __shfl_xor(part1, 32);
        const float bov = bo[0];
        if (h == 0) {
            if (pt0 < n) out[pt0] = part0 + bov;
            if (pt1 < n) out[pt1] = part1 + bov;
        }
    }
}

extern "C" void kernel_launch(void* const* d_in, const int* in_sizes, int n_in,
                              void* d_out, int out_size, void* d_ws, size_t ws_size,
                              hipStream_t stream) {
    const float* points = (const float*)d_in[0];
    const float* w0     = (const float*)d_in[1];
    const float* s0     = (const float*)d_in[2];
    const float* b0     = (const float*)d_in[3];
    const float* wh     = (const float*)d_in[4];
    const float* sh     = (const float*)d_in[5];
    const float* bh     = (const float*)d_in[6];
    const float* wo     = (const float*)d_in[7];
    const float* so     = (const float*)d_in[8];
    const float* bo     = (const float*)d_in[9];

    const int n = in_sizes[0] / 3;

    setup_weights<<<(SETUP_TOTAL + 255) / 256, 256, 0, stream>>>(
        w0, s0, b0, wh, sh, bh, wo, so, (unsigned char*)d_ws);

    const int grid = (n + 511) / 512;  // 512 points per block (8 waves x 64)
    mlp_mfma<<<grid, 512, 0, stream>>>(
        points, (const unsigned char*)d_ws, bo, (float*)d_out, n);
}

// Round 2
// 128.229 us; speedup vs baseline: 1.0375x; 1.0049x over previous
//
#include <hip/hip_runtime.h>

// ImplicitFunction MLP via fp16 MFMA (v_mfma_f32_32x32x16_f16), round 6.
// Round-6 changes (VALU-cut attack; pipes were 92% serialized, VALU=51% the
// larger share):
//  - Output layer moved onto the MFMA pipe: wo pre-permuted+broadcast to all
//    32 A-rows in setup; 4 chained MFMAs per n-tile replace the 192-op fp32
//    dot + cross-half shuffles. (Same feat k-slot mapping as hidden layers.)
//  - Packed activations stored directly as int4v frv[2][4] (constant-indexed
//    ext-vectors): MFMA B-operand is a pure bitcast, no FragU marshalling movs.
//  - s_setprio(1) around each MFMA cluster (T5) to decorrelate wave phases.
//
// Carried: K-permuted weights (exchange-free layer transition), bias in MFMA
// C-operand, packed-fp16 lrelu, activations scaled 1/64, 64 pts/wave,
// 512-thread blocks, __launch_bounds__(512,4).
//
// Layouts (gfx950, 32x32x16):
//   A/B frag: lane (i=lane&31, h=lane>>5) holds k = 8h+j, j=0..7
//   C/D:      col n = lane&31, row m = (r&3) + 8*(r>>2) + 4h, r=0..15
//   k-slot:   feat(s,h,j) = 16s + 8*(j>>2) + 4h + (j&3)

typedef _Float16 half8 __attribute__((ext_vector_type(8)));
typedef _Float16 half2v __attribute__((ext_vector_type(2)));
typedef float floatx16 __attribute__((ext_vector_type(16)));
typedef int int4v __attribute__((ext_vector_type(4)));

#define N_HID 6
// ws / LDS byte offsets (single contiguous image, staged wholesale)
#define OFF_A 0        // hidden W frags [l:6][t:2][s:4][lane:64][j:8] fp16 = 49152
#define OFF_B 49152    // layer0 A frags [t:2][lane:64][j:8] fp16          = 2048
#define OFF_C 51200    // bias/64 fp32, C-layout [l:7][h:2][t:2][r:16]     = 1792
#define OFF_D 52992    // wo*so*64 fp16 A-frags [s:4][lane:64][j:8]        = 4096
#define IMG_BYTES 57088
#define SETUP_TOTAL (24576 + 1024 + 448 + 2048)

__global__ __launch_bounds__(256) void setup_weights(
    const float* __restrict__ w0, const float* __restrict__ s0, const float* __restrict__ b0,
    const float* __restrict__ wh, const float* __restrict__ sh, const float* __restrict__ bh,
    const float* __restrict__ wo, const float* __restrict__ so,
    unsigned char* __restrict__ ws)
{
    int i = blockIdx.x * 256 + threadIdx.x;
    if (i < 24576) {
        // hidden W frags with K-permutation baked in:
        // A[m][kslot(s,h,j)] = wh[l][feat][m] * sh[l][m], feat = 16s+8*(j>>2)+4h+(j&3)
        int j = i & 7, lane = (i >> 3) & 63, s = (i >> 9) & 3, t = (i >> 11) & 1, l = i >> 12;
        int m = 32 * t + (lane & 31);
        int h = lane >> 5;
        int feat = 16 * s + 8 * (j >> 2) + 4 * h + (j & 3);
        ((_Float16*)(ws + OFF_A))[i] = (_Float16)(wh[(l * 64 + feat) * 64 + m] * sh[l * 64 + m]);
    } else if (i < 24576 + 1024) {
        // layer-0 A frags (standard k order; B built from raw points)
        int i2 = i - 24576;
        int j = i2 & 7, lane = (i2 >> 3) & 63, t = i2 >> 9;
        int m = 32 * t + (lane & 31);
        int k = 8 * (lane >> 5) + j;
        float v = (k < 3) ? w0[k * 64 + m] * s0[m] * 0.015625f : 0.f;
        ((_Float16*)(ws + OFF_B))[i2] = (_Float16)v;
    } else if (i < 24576 + 1024 + 448) {
        // biases/64 in C layout
        int i2 = i - 24576 - 1024;
        int r = i2 & 15, t = (i2 >> 4) & 1, h = (i2 >> 5) & 1, l = i2 >> 6;
        int feat = 32 * t + (r & 3) + 8 * ((r >> 2) & 3) + 4 * h;
        float bv = (l == 0) ? b0[feat] : bh[(l - 1) * 64 + feat];
        ((float*)(ws + OFF_C))[i2] = bv * 0.015625f;
    } else if (i < SETUP_TOTAL) {
        // wo*so*64 as fp16 A-frags, broadcast to all 32 rows, k-slot permuted
        int i2 = i - (24576 + 1024 + 448);
        int j = i2 & 7, lane = (i2 >> 3) & 63, s = i2 >> 9;
        int h = lane >> 5;
        int feat = 16 * s + 8 * (j >> 2) + 4 * h + (j & 3);
        ((_Float16*)(ws + OFF_D))[i2] = (_Float16)(wo[feat] * so[0] * 64.f);
    }
}

static __device__ __forceinline__ int pkrtz(float a, float b) {
    auto hh = __builtin_amdgcn_cvt_pkrtz(a, b);  // v2f16, RTZ pack
    int r;
    __builtin_memcpy(&r, &hh, 4);
    return r;
}

// packed-fp16 leaky relu on a pair: max(u, 0.2*u) -> v_pk_mul_f16 + v_pk_max_f16
static __device__ __forceinline__ int lrelu2(int v) {
    half2v u;
    __builtin_memcpy(&u, &v, 4);
    half2v w = u * (_Float16)0.2f;
    half2v r = __builtin_elementwise_max(u, w);
    int o;
    __builtin_memcpy(&o, &r, 4);
    return o;
}

static __device__ __forceinline__ half8 as_h8(int4v v) {
    half8 r;
    __builtin_memcpy(&r, &v, 16);
    return r;
}

static __device__ __forceinline__ floatx16 mfma16(half8 a, half8 b, floatx16 c) {
    return __builtin_amdgcn_mfma_f32_32x32x16_f16(a, b, c, 0, 0, 0);
}

__global__ __launch_bounds__(512, 4) void mlp_mfma(
    const float* __restrict__ points,
    const unsigned char* __restrict__ ws,
    const float* __restrict__ bo,
    float* __restrict__ out, int n)
{
    __shared__ __align__(16) unsigned char lds[IMG_BYTES];

    // stage full weight image to LDS (57088 B = 3568 * 16; 512 threads)
    {
        const uint4* src = (const uint4*)ws;
        uint4* dst = (uint4*)lds;
#pragma unroll
        for (int i = 0; i < 6; ++i) {
            int idx = threadIdx.x + 512 * i;
            dst[idx] = src[idx];
        }
        if (threadIdx.x < 496) {
            int idx = 3072 + threadIdx.x;
            dst[idx] = src[idx];
        }
    }
    __syncthreads();

    const int lane = threadIdx.x & 63;
    const int wv = threadIdx.x >> 6;   // 0..7 (8 waves/block)
    const int p = lane & 31;
    const int h = lane >> 5;
    const int base = (blockIdx.x * 8 + wv) * 64;
    const int pt0 = base + p, pt1 = base + 32 + p;
    const int pl0 = min(pt0, n - 1), pl1 = min(pt1, n - 1);

    const half8* Wf = (const half8*)(lds + OFF_A);          // [l][t][s][lane]
    const half8* A0 = (const half8*)(lds + OFF_B);          // [t][lane]
    const floatx16* biasC = (const floatx16*)(lds + OFF_C); // [(l*2+h)*2+t]
    const half8* woA = (const half8*)(lds + OFF_D);         // [s][lane]

    floatx16 acc[2][2];   // [ntile][mtile]
    int4v frv[2][4];      // packed activations, [ntile][kstep] = B-frag

    // ---- layer 0 ----
    {
        int4v z4 = {0, 0, 0, 0};
        int4v b0v = z4, b1v = z4;
        if (h == 0) {
            b0v[0] = pkrtz(points[3 * pl0 + 0], points[3 * pl0 + 1]);
            b0v[1] = pkrtz(points[3 * pl0 + 2], 0.f);
            b1v[0] = pkrtz(points[3 * pl1 + 0], points[3 * pl1 + 1]);
            b1v[1] = pkrtz(points[3 * pl1 + 2], 0.f);
        }
        floatx16 c0 = biasC[h * 2 + 0];   // l = 0
        floatx16 c1 = biasC[h * 2 + 1];
        half8 a0 = A0[lane], a1 = A0[64 + lane];
        __builtin_amdgcn_s_setprio(1);
        acc[0][0] = mfma16(a0, as_h8(b0v), c0);
        acc[0][1] = mfma16(a1, as_h8(b0v), c1);
        acc[1][0] = mfma16(a0, as_h8(b1v), c0);
        acc[1][1] = mfma16(a1, as_h8(b1v), c1);
        __builtin_amdgcn_s_setprio(0);
    }

    // pack + lrelu -> frv (also the next layer's B-frags, exchange-free)
    auto packfr = [&]() {
#pragma unroll
        for (int nt = 0; nt < 2; ++nt)
#pragma unroll
            for (int t = 0; t < 2; ++t)
#pragma unroll
                for (int rp = 0; rp < 8; ++rp) {
                    int v = pkrtz(acc[nt][t][2 * rp], acc[nt][t][2 * rp + 1]);
                    int idx = 8 * t + rp;
                    frv[nt][idx >> 2][idx & 3] = lrelu2(v);
                }
    };
    packfr();

    // ---- 6 hidden layers ----
    for (int l = 0; l < N_HID; ++l) {
        const floatx16 c0 = biasC[((l + 1) * 2 + h) * 2 + 0];
        const floatx16 c1 = biasC[((l + 1) * 2 + h) * 2 + 1];
        const half8* wl = Wf + l * 512 + lane;  // + t*256 + s*64
        __builtin_amdgcn_s_setprio(1);
        {
            half8 w0 = wl[0], w1 = wl[256];
            half8 f0 = as_h8(frv[0][0]), f1 = as_h8(frv[1][0]);
            acc[0][0] = mfma16(w0, f0, c0);
            acc[0][1] = mfma16(w1, f0, c1);
            acc[1][0] = mfma16(w0, f1, c0);
            acc[1][1] = mfma16(w1, f1, c1);
        }
#pragma unroll
        for (int s = 1; s < 4; ++s) {
            half8 w0 = wl[s * 64], w1 = wl[256 + s * 64];
            half8 f0 = as_h8(frv[0][s]), f1 = as_h8(frv[1][s]);
            acc[0][0] = mfma16(w0, f0, acc[0][0]);
            acc[0][1] = mfma16(w1, f0, acc[0][1]);
            acc[1][0] = mfma16(w0, f1, acc[1][0]);
            acc[1][1] = mfma16(w1, f1, acc[1][1]);
        }
        __builtin_amdgcn_s_setprio(0);
        packfr();   // all 6 layers: last one feeds the MFMA output layer
    }

    // ---- output layer on the MFMA pipe ----
    // woA rows are all wo (broadcast): D[m][n] = sum_feat wo[feat]*act[n][feat]
    // for every m, so any D element of the chain result is the output.
    {
        floatx16 z;
#pragma unroll
        for (int r = 0; r < 16; ++r) z[r] = 0.f;
        floatx16 o0 = z, o1 = z;
        __builtin_amdgcn_s_setprio(1);
#pragma unroll
        for (int s = 0; s < 4; ++s) {
            half8 w = woA[s * 64 + lane];
            o0 = mfma16(w, as_h8(frv[0][s]), o0);
            o1 = mfma16(w, as_h8(frv[1][s]), o1);
        }
        __builtin_amdgcn_s_setprio(0);
        const float bov = bo[0];
        if (h == 0) {
            if (pt0 < n) out[pt0] = o0[0] + bov;
            if (pt1 < n) out[pt1] = o1[0] + bov;
        }
    }
}

extern "C" void kernel_launch(void* const* d_in, const int* in_sizes, int n_in,
                              void* d_out, int out_size, void* d_ws, size_t ws_size,
                              hipStream_t stream) {
    const float* points = (const float*)d_in[0];
    const float* w0     = (const float*)d_in[1];
    const float* s0     = (const float*)d_in[2];
    const float* b0     = (const float*)d_in[3];
    const float* wh     = (const float*)d_in[4];
    const float* sh     = (const float*)d_in[5];
    const float* bh     = (const float*)d_in[6];
    const float* wo     = (const float*)d_in[7];
    const float* so     = (const float*)d_in[8];
    const float* bo     = (const float*)d_in[9];

    const int n = in_sizes[0] / 3;

    setup_weights<<<(SETUP_TOTAL + 255) / 256, 256, 0, stream>>>(
        w0, s0, b0, wh, sh, bh, wo, so, (unsigned char*)d_ws);

    const int grid = (n + 511) / 512;  // 512 points per block (8 waves x 64)
    mlp_mfma<<<grid, 512, 0, stream>>>(
        points, (const unsigned char*)d_ws, bo, (float*)d_out, n);
}